// Round 6
// baseline (1276.761 us; speedup 1.0000x reference)
//
#include <hip/hip_runtime.h>
#include <hip/hip_fp16.h>

#define NN 100000     // num nodes
#define NE 1600000    // num edges
#define NEL 200000    // link-pred edges

// Bucketed CSR build (R20 config): bucket = dst >> 8 (256 nodes).
#define NBUCK 391     // ceil(NN/256)
#define CAPB  4800    // per-bucket capacity (mean 4096, sigma 64 -> 11 sigma)
#define TPE   2048    // edges per part tile (782 tiles)
#define EPT   8       // edges per thread in part (TPE/256)
#define NPART 782     // ceil(NE/TPE)

#define GRID  768     // persistent blocks: 3/CU, LDS 37.1KB -> >=4/CU fits,
                      // co-residency margin 2x. 768x4 waves x16-deep = 49k
                      // lines in flight for gathers (>= ~14k saturation need).
#define NT    256

typedef short s16x8 __attribute__((ext_vector_type(8)));
typedef float f32x4 __attribute__((ext_vector_type(4)));

__device__ __forceinline__ unsigned short bf16hi(float v) {
    unsigned u = __float_as_uint(v);
    return (unsigned short)((u + 0x7FFFu + ((u >> 16) & 1u)) >> 16);
}
__device__ __forceinline__ float bf16tof(unsigned short b) {
    return __uint_as_float(((unsigned)b) << 16);
}

// Device-scope grid barrier: monotone counter (zeroed by the memset node
// each launch). Release/acquire atomics at AGENT scope + __threadfence on
// both sides (L2 writeback + invalidate) for cross-XCD visibility.
__device__ __forceinline__ void gbar(int* bar, int target) {
    __syncthreads();
    if (threadIdx.x == 0) {
        __threadfence();
        __hip_atomic_fetch_add(bar, 1, __ATOMIC_RELEASE, __HIP_MEMORY_SCOPE_AGENT);
        while (__hip_atomic_load(bar, __ATOMIC_ACQUIRE, __HIP_MEMORY_SCOPE_AGENT) < target)
            __builtin_amdgcn_s_sleep(4);
        __threadfence();
    }
    __syncthreads();
}

// LDS union across phases; max member = hw1 (37.1 KB).
union Smem {
    struct { int hist[NBUCK], base[NBUCK], rk[NBUCK]; } part;              // 4.7 KB
    struct { int cnts[512], hist[256], loff[256], ssum[128], csrbuf[CAPB]; } build; // 23.3 KB
    struct { unsigned short ahi[32*104], alo[32*104],                      // A stride 104 (conflict-free)
                            bhi[64*96],  blo[64*96];                       // B stride 96 (8-way, ~2us total)
             float sdin[32]; } h1;                                         // 37.1 KB
    struct { unsigned short ahi[64*72], alo[64*72], bhi[32*72], blo[32*72];
             float sdin[64]; } h2s;                                        // 27.3 KB
};

__global__ __launch_bounds__(NT, 4) void k_mega(
        const int* __restrict__ src, const int* __restrict__ dst,
        const float* __restrict__ x, const float* __restrict__ pos,
        const float* __restrict__ W1, const float* __restrict__ b1,
        const float* __restrict__ W2, const float* __restrict__ b2,
        const float* __restrict__ Wl, const float* __restrict__ bl,
        const int* __restrict__ lsrc, const int* __restrict__ ldst,
        int* __restrict__ gcur, int* __restrict__ bar,
        int* __restrict__ part, int* __restrict__ csr,
        int* __restrict__ off, float* __restrict__ dinv,
        __half* __restrict__ hw1, __half* __restrict__ h2,
        __half* __restrict__ hw2, float* __restrict__ uu,
        float* __restrict__ vv, float* __restrict__ outz,
        float* __restrict__ pred) {
    __shared__ Smem sm;
    int tid = threadIdx.x;
    int bid = blockIdx.x;

    // ---- phase 1: partition edges into buckets (register-staged) ----------
    for (int vt = bid; vt < NPART; vt += GRID) {
        for (int i = tid; i < NBUCK; i += NT) { sm.part.hist[i] = 0; sm.part.rk[i] = 0; }
        __syncthreads();
        int e0 = vt * TPE;
        int d[EPT], s[EPT];
#pragma unroll
        for (int k = 0; k < EPT; ++k) {
            int e = e0 + tid + k * NT;
            bool ok = e < NE;
            d[k] = ok ? dst[e] : -1;
            s[k] = ok ? src[e] : 0;
        }
#pragma unroll
        for (int k = 0; k < EPT; ++k)
            if (d[k] >= 0) atomicAdd(&sm.part.hist[d[k] >> 8], 1);
        __syncthreads();
        for (int i = tid; i < NBUCK; i += NT)
            if (sm.part.hist[i])
                sm.part.base[i] = i * CAPB + atomicAdd(&gcur[i], sm.part.hist[i]);
        __syncthreads();
#pragma unroll
        for (int k = 0; k < EPT; ++k)
            if (d[k] >= 0) {
                int b = d[k] >> 8;
                int r = atomicAdd(&sm.part.rk[b], 1);
                part[sm.part.base[b] + r] = ((d[k] & 255) << 17) | s[k];  // src < 2^17
            }
        __syncthreads();
    }
    gbar(bar, GRID * 1);

    // ---- phase 2: per-bucket LDS sort -> csr/off/dinv ---------------------
    for (int vt = bid; vt < NBUCK; vt += GRID) {
        int t2 = tid + 256;
        sm.build.cnts[tid] = (tid < NBUCK) ? gcur[tid] : 0;
        sm.build.cnts[t2]  = (t2  < NBUCK) ? gcur[t2]  : 0;
        __syncthreads();
        for (int st = 1; st < 512; st <<= 1) {
            int a = (tid >= st) ? sm.build.cnts[tid - st] : 0;
            int c = sm.build.cnts[t2 - st];
            __syncthreads();
            sm.build.cnts[tid] += a;
            sm.build.cnts[t2]  += c;
            __syncthreads();
        }
        int obase = (vt == 0) ? 0 : sm.build.cnts[vt - 1];
        int cnt = gcur[vt];
        int pbase = vt * CAPB;
        sm.build.hist[tid] = 0;
        __syncthreads();
        for (int i = tid; i < cnt; i += NT)
            atomicAdd(&sm.build.hist[part[pbase + i] >> 17], 1);
        __syncthreads();
        int a0 = 0, a1 = 0, pairs = 0;
        if (tid < 128) {
            a0 = sm.build.hist[2 * tid]; a1 = sm.build.hist[2 * tid + 1];
            pairs = a0 + a1;
            sm.build.ssum[tid] = pairs;
        }
        __syncthreads();
        for (int st = 1; st < 128; st <<= 1) {
            int tmp = (tid >= st && tid < 128) ? sm.build.ssum[tid - st] : 0;
            __syncthreads();
            if (tid < 128) sm.build.ssum[tid] += tmp;
            __syncthreads();
        }
        if (tid < 128) {
            int pexcl = sm.build.ssum[tid] - pairs;
            sm.build.loff[2 * tid] = pexcl;
            sm.build.loff[2 * tid + 1] = pexcl + a0;
        }
        __syncthreads();
        {
            int dnode = vt * 256 + tid;
            if (dnode < NN) {
                int c = sm.build.hist[tid];
                off[dnode] = obase + sm.build.loff[tid] + c;   // end of row d
                dinv[dnode] = rsqrtf((float)(c + 1));          // +1 self-loop
            }
        }
        __syncthreads();
        sm.build.hist[tid] = 0;                                // rank counters
        __syncthreads();
        for (int i = tid; i < cnt; i += NT) {
            int rec = part[pbase + i];
            int dl = rec >> 17;
            int r = atomicAdd(&sm.build.hist[dl], 1);
            sm.build.csrbuf[sm.build.loff[dl] + r] = rec & 0x1FFFF;
        }
        __syncthreads();
        for (int i = tid; i < cnt; i += NT)                    // coalesced flush
            csr[obase + i] = sm.build.csrbuf[i];
        __syncthreads();
    }
    gbar(bar, GRID * 2);

    // ---- phase 3: hw1' = dinv * ([x|pos] @ W1), MFMA bf16-split -----------
    {
        // stage B (W1^T, hi/lo) once; zero pads once (k=80..95 for B, 80..103 A)
        for (int i = tid; i < 64 * 16; i += NT) {
            int c = i >> 4, k = 80 + (i & 15);
            sm.h1.bhi[c * 96 + k] = 0; sm.h1.blo[c * 96 + k] = 0;
        }
        for (int i = tid; i < 32 * 24; i += NT) {
            int r = i / 24, k = 80 + (i - r * 24);
            sm.h1.ahi[r * 104 + k] = 0; sm.h1.alo[r * 104 + k] = 0;
        }
        for (int i = tid; i < 80 * 64; i += NT) {
            int k = i >> 6, c = i & 63;
            float v = W1[i];
            unsigned short h = bf16hi(v);
            sm.h1.bhi[c * 96 + k] = h;
            sm.h1.blo[c * 96 + k] = bf16hi(v - bf16tof(h));
        }
        __syncthreads();
        for (int vt = bid; vt < (NN + 31) / 32; vt += GRID) {
            int nb = vt * 32;
            for (int i = tid; i < 32 * 64; i += NT) {
                int r = i >> 6, c = i & 63;
                int g = nb + r;
                float v = (g < NN) ? x[g * 64 + c] : 0.0f;
                unsigned short h = bf16hi(v);
                sm.h1.ahi[r * 104 + c] = h;
                sm.h1.alo[r * 104 + c] = bf16hi(v - bf16tof(h));
            }
            for (int i = tid; i < 32 * 16; i += NT) {
                int r = i >> 4, c = i & 15;
                int g = nb + r;
                float v = (g < NN) ? pos[g * 16 + c] : 0.0f;
                unsigned short h = bf16hi(v);
                sm.h1.ahi[r * 104 + 64 + c] = h;
                sm.h1.alo[r * 104 + 64 + c] = bf16hi(v - bf16tof(h));
            }
            for (int i = tid; i < 32; i += NT) {
                int g = nb + i;
                sm.h1.sdin[i] = (g < NN) ? dinv[g] : 0.0f;
            }
            __syncthreads();
            int w = tid >> 6, lane = tid & 63;
            int frow = lane & 15, fq = lane >> 4;
            int r0 = (w & 1) * 16;
            int ct0 = (w >> 1) * 2;
            int aoff = (r0 + frow) * 104 + fq * 8;
            s16x8 ah0 = *(s16x8*)&sm.h1.ahi[aoff];
            s16x8 ah1 = *(s16x8*)&sm.h1.ahi[aoff + 32];
            s16x8 ah2 = *(s16x8*)&sm.h1.ahi[aoff + 64];
            s16x8 al0 = *(s16x8*)&sm.h1.alo[aoff];
            s16x8 al1 = *(s16x8*)&sm.h1.alo[aoff + 32];
            s16x8 al2 = *(s16x8*)&sm.h1.alo[aoff + 64];
#pragma unroll
            for (int ci = 0; ci < 2; ++ci) {
                int c = (ct0 + ci) * 16 + frow;
                int boff = c * 96 + fq * 8;
                s16x8 bh0 = *(s16x8*)&sm.h1.bhi[boff];
                s16x8 bh1 = *(s16x8*)&sm.h1.bhi[boff + 32];
                s16x8 bh2 = *(s16x8*)&sm.h1.bhi[boff + 64];
                s16x8 bl0 = *(s16x8*)&sm.h1.blo[boff];
                s16x8 bl1 = *(s16x8*)&sm.h1.blo[boff + 32];
                s16x8 bl2 = *(s16x8*)&sm.h1.blo[boff + 64];
                f32x4 acc = (f32x4)(0.0f);
                acc = __builtin_amdgcn_mfma_f32_16x16x32_bf16(ah0, bh0, acc, 0, 0, 0);
                acc = __builtin_amdgcn_mfma_f32_16x16x32_bf16(ah1, bh1, acc, 0, 0, 0);
                acc = __builtin_amdgcn_mfma_f32_16x16x32_bf16(ah2, bh2, acc, 0, 0, 0);
                acc = __builtin_amdgcn_mfma_f32_16x16x32_bf16(ah0, bl0, acc, 0, 0, 0);
                acc = __builtin_amdgcn_mfma_f32_16x16x32_bf16(ah1, bl1, acc, 0, 0, 0);
                acc = __builtin_amdgcn_mfma_f32_16x16x32_bf16(ah2, bl2, acc, 0, 0, 0);
                acc = __builtin_amdgcn_mfma_f32_16x16x32_bf16(al0, bh0, acc, 0, 0, 0);
                acc = __builtin_amdgcn_mfma_f32_16x16x32_bf16(al1, bh1, acc, 0, 0, 0);
                acc = __builtin_amdgcn_mfma_f32_16x16x32_bf16(al2, bh2, acc, 0, 0, 0);
                int col = c;
#pragma unroll
                for (int i = 0; i < 4; ++i) {
                    int r = r0 + fq * 4 + i;     // C/D: col=lane&15, row=(lane>>4)*4+i
                    int g = nb + r;
                    if (g < NN)
                        hw1[g * 64 + col] = __float2half_rn(acc[i] * sm.h1.sdin[r]);
                }
            }
            __syncthreads();
        }
    }
    gbar(bar, GRID * 3);

    // ---- phase 4: layer-1 gather (masked 16-deep, tail-free) --------------
    for (int vt = bid; vt < NN / 4; vt += GRID) {
        int lane = tid & 63;
        int wave = tid >> 6;
        int d = vt * 4 + wave;
        int start = (d == 0) ? 0 : off[d - 1];
        int end = off[d];
        start = __builtin_amdgcn_readfirstlane(start);
        end   = __builtin_amdgcn_readfirstlane(end);
        float dd = dinv[d];
        float hself = __half2float(hw1[d * 64 + lane]);
        float acc0 = 0.0f, acc1 = 0.0f, acc2 = 0.0f, acc3 = 0.0f;
        for (int e = start; e < end; e += 16) {
            int rem = end - e;
            int s0 = csr[e];
            int s1  = (rem > 1)  ? csr[e + 1]  : s0;
            int s2  = (rem > 2)  ? csr[e + 2]  : s0;
            int s3  = (rem > 3)  ? csr[e + 3]  : s0;
            int s4  = (rem > 4)  ? csr[e + 4]  : s0;
            int s5  = (rem > 5)  ? csr[e + 5]  : s0;
            int s6  = (rem > 6)  ? csr[e + 6]  : s0;
            int s7  = (rem > 7)  ? csr[e + 7]  : s0;
            int s8  = (rem > 8)  ? csr[e + 8]  : s0;
            int s9  = (rem > 9)  ? csr[e + 9]  : s0;
            int s10 = (rem > 10) ? csr[e + 10] : s0;
            int s11 = (rem > 11) ? csr[e + 11] : s0;
            int s12 = (rem > 12) ? csr[e + 12] : s0;
            int s13 = (rem > 13) ? csr[e + 13] : s0;
            int s14 = (rem > 14) ? csr[e + 14] : s0;
            int s15 = (rem > 15) ? csr[e + 15] : s0;
            float g0  = __half2float(hw1[s0  * 64 + lane]);
            float g1  = __half2float(hw1[s1  * 64 + lane]);
            float g2  = __half2float(hw1[s2  * 64 + lane]);
            float g3  = __half2float(hw1[s3  * 64 + lane]);
            float g4  = __half2float(hw1[s4  * 64 + lane]);
            float g5  = __half2float(hw1[s5  * 64 + lane]);
            float g6  = __half2float(hw1[s6  * 64 + lane]);
            float g7  = __half2float(hw1[s7  * 64 + lane]);
            float g8  = __half2float(hw1[s8  * 64 + lane]);
            float g9  = __half2float(hw1[s9  * 64 + lane]);
            float g10 = __half2float(hw1[s10 * 64 + lane]);
            float g11 = __half2float(hw1[s11 * 64 + lane]);
            float g12 = __half2float(hw1[s12 * 64 + lane]);
            float g13 = __half2float(hw1[s13 * 64 + lane]);
            float g14 = __half2float(hw1[s14 * 64 + lane]);
            float g15 = __half2float(hw1[s15 * 64 + lane]);
            int inv = 16 - rem;
            if (inv < 0) inv = 0;
            acc0 += g0;  acc1 += g1;  acc2 += g2;  acc3 += g3;
            acc0 += g4;  acc1 += g5;  acc2 += g6;  acc3 += g7;
            acc0 += g8;  acc1 += g9;  acc2 += g10; acc3 += g11;
            acc0 += g12; acc1 += g13; acc2 += g14; acc3 += g15;
            acc3 = fmaf(-(float)inv, g0, acc3);
        }
        float v = fmaxf(b1[lane] + dd * (((acc0 + acc1) + (acc2 + acc3)) + hself), 0.0f);
        h2[d * 64 + lane] = __float2half_rn(v);
    }
    gbar(bar, GRID * 4);

    // ---- phase 5: hw2' = dinv * (h2 @ W2), MFMA bf16-split ----------------
    {
        for (int i = tid; i < 32 * 8; i += NT) {             // B pad k=64..71
            int c = i >> 3, k = 64 + (i & 7);
            sm.h2s.bhi[c * 72 + k] = 0; sm.h2s.blo[c * 72 + k] = 0;
        }
        for (int i = tid; i < 64 * 8; i += NT) {             // A pad k=64..71
            int r = i >> 3, k = 64 + (i & 7);
            sm.h2s.ahi[r * 72 + k] = 0; sm.h2s.alo[r * 72 + k] = 0;
        }
        for (int i = tid; i < 64 * 32; i += NT) {
            int k = i >> 5, c = i & 31;
            float v = W2[i];
            unsigned short h = bf16hi(v);
            sm.h2s.bhi[c * 72 + k] = h;
            sm.h2s.blo[c * 72 + k] = bf16hi(v - bf16tof(h));
        }
        __syncthreads();
        for (int vt = bid; vt < (NN + 63) / 64; vt += GRID) {
            int nb = vt * 64;
            for (int i = tid; i < 64 * 32; i += NT) {
                int r = i >> 5, cp = i & 31;
                int g = nb + r;
                __half2 hv = (g < NN) ? ((const __half2*)h2)[g * 32 + cp]
                                      : __floats2half2_rn(0.0f, 0.0f);
                float2 f = __half22float2(hv);
                unsigned short h0 = bf16hi(f.x), h1 = bf16hi(f.y);
                sm.h2s.ahi[r * 72 + 2 * cp]     = h0;
                sm.h2s.ahi[r * 72 + 2 * cp + 1] = h1;
                sm.h2s.alo[r * 72 + 2 * cp]     = bf16hi(f.x - bf16tof(h0));
                sm.h2s.alo[r * 72 + 2 * cp + 1] = bf16hi(f.y - bf16tof(h1));
            }
            for (int i = tid; i < 64; i += NT) {
                int g = nb + i;
                sm.h2s.sdin[i] = (g < NN) ? dinv[g] : 0.0f;
            }
            __syncthreads();
            int w = tid >> 6, lane = tid & 63;
            int frow = lane & 15, fq = lane >> 4;
            int r0 = w * 16;
            int aoff = (r0 + frow) * 72 + fq * 8;
            s16x8 ah0 = *(s16x8*)&sm.h2s.ahi[aoff];
            s16x8 ah1 = *(s16x8*)&sm.h2s.ahi[aoff + 32];
            s16x8 al0 = *(s16x8*)&sm.h2s.alo[aoff];
            s16x8 al1 = *(s16x8*)&sm.h2s.alo[aoff + 32];
#pragma unroll
            for (int ci = 0; ci < 2; ++ci) {
                int c = ci * 16 + frow;
                int boff = c * 72 + fq * 8;
                s16x8 bh0 = *(s16x8*)&sm.h2s.bhi[boff];
                s16x8 bh1 = *(s16x8*)&sm.h2s.bhi[boff + 32];
                s16x8 bl0 = *(s16x8*)&sm.h2s.blo[boff];
                s16x8 bl1 = *(s16x8*)&sm.h2s.blo[boff + 32];
                f32x4 acc = (f32x4)(0.0f);
                acc = __builtin_amdgcn_mfma_f32_16x16x32_bf16(ah0, bh0, acc, 0, 0, 0);
                acc = __builtin_amdgcn_mfma_f32_16x16x32_bf16(ah1, bh1, acc, 0, 0, 0);
                acc = __builtin_amdgcn_mfma_f32_16x16x32_bf16(ah0, bl0, acc, 0, 0, 0);
                acc = __builtin_amdgcn_mfma_f32_16x16x32_bf16(ah1, bl1, acc, 0, 0, 0);
                acc = __builtin_amdgcn_mfma_f32_16x16x32_bf16(al0, bh0, acc, 0, 0, 0);
                acc = __builtin_amdgcn_mfma_f32_16x16x32_bf16(al1, bh1, acc, 0, 0, 0);
#pragma unroll
                for (int i = 0; i < 4; ++i) {
                    int r = r0 + fq * 4 + i;
                    int g = nb + r;
                    if (g < NN)
                        hw2[g * 32 + c] = __float2half_rn(acc[i] * sm.h2s.sdin[r]);
                }
            }
            __syncthreads();
        }
    }
    gbar(bar, GRID * 5);

    // ---- phase 6: layer-2 gather + z + linkpred dots ----------------------
    for (int vt = bid; vt < NN / 4; vt += GRID) {
        int lane = tid & 63;
        int half = lane >> 5;
        int j = lane & 31;
        int wave = tid >> 6;
        int d = vt * 4 + wave;
        int start = (d == 0) ? 0 : off[d - 1];
        int end = off[d];
        start = __builtin_amdgcn_readfirstlane(start);
        end   = __builtin_amdgcn_readfirstlane(end);
        float dd = dinv[d];
        float hself = __half2float(hw2[d * 32 + j]);
        float accA = 0.0f, accB = 0.0f, accC = 0.0f, accD = 0.0f;
        for (int e = start; e < end; e += 16) {
            int rem = end - e;
            int s0 = csr[e];
            int i1 = e + half;
            int sA = (half      < rem) ? csr[i1]      : s0;
            int sB = (half + 2  < rem) ? csr[i1 + 2]  : s0;
            int sC = (half + 4  < rem) ? csr[i1 + 4]  : s0;
            int sD = (half + 6  < rem) ? csr[i1 + 6]  : s0;
            int sE = (half + 8  < rem) ? csr[i1 + 8]  : s0;
            int sF = (half + 10 < rem) ? csr[i1 + 10] : s0;
            int sG = (half + 12 < rem) ? csr[i1 + 12] : s0;
            int sH = (half + 14 < rem) ? csr[i1 + 14] : s0;
            float gA = __half2float(hw2[sA * 32 + j]);
            float gB = __half2float(hw2[sB * 32 + j]);
            float gC = __half2float(hw2[sC * 32 + j]);
            float gD = __half2float(hw2[sD * 32 + j]);
            float gE = __half2float(hw2[sE * 32 + j]);
            float gF = __half2float(hw2[sF * 32 + j]);
            float gG = __half2float(hw2[sG * 32 + j]);
            float gH = __half2float(hw2[sH * 32 + j]);
            int nv = (rem - half + 1) >> 1;
            if (nv > 8) nv = 8;
            int inv = 8 - nv;
            accA += gA; accB += gB; accC += gC; accD += gD;
            accA += gE; accB += gF; accC += gG; accD += gH;
            accD = fmaf(-(float)inv, gH, accD);
        }
        float acc = (accA + accB) + (accC + accD);
        acc += __shfl(acc, lane ^ 32, 64);
        float z = b2[j] + dd * (acc + hself);
        if (half == 0)
            outz[d * 32 + j] = z;
        float p0 = z * Wl[j];
        float p1 = z * Wl[32 + j];
        p0 += __shfl_xor(p0, 1, 64);  p1 += __shfl_xor(p1, 1, 64);
        p0 += __shfl_xor(p0, 2, 64);  p1 += __shfl_xor(p1, 2, 64);
        p0 += __shfl_xor(p0, 4, 64);  p1 += __shfl_xor(p1, 4, 64);
        p0 += __shfl_xor(p0, 8, 64);  p1 += __shfl_xor(p1, 8, 64);
        p0 += __shfl_xor(p0, 16, 64); p1 += __shfl_xor(p1, 16, 64);
        if (lane == 0) { uu[d] = p0; vv[d] = p1; }
    }
    gbar(bar, GRID * 6);

    // ---- phase 7: link prediction: pred = u[s] + v[d] + bl ----------------
    for (int vt = bid; vt < (NEL + NT - 1) / NT; vt += GRID) {
        int e = vt * NT + tid;
        if (e < NEL)
            pred[e] = uu[lsrc[e]] + vv[ldst[e]] + bl[0];
    }
}

extern "C" void kernel_launch(void* const* d_in, const int* in_sizes, int n_in,
                              void* d_out, int out_size, void* d_ws, size_t ws_size,
                              hipStream_t stream) {
    const float* x    = (const float*)d_in[0];
    const float* pos  = (const float*)d_in[1];
    const float* W1   = (const float*)d_in[2];
    const float* b1   = (const float*)d_in[3];
    const float* W2   = (const float*)d_in[4];
    const float* b2   = (const float*)d_in[5];
    const float* Wl   = (const float*)d_in[6];
    const float* bl   = (const float*)d_in[7];
    const int*   ei   = (const int*)d_in[8];   // [2, NE]
    const int*   eli  = (const int*)d_in[9];   // [2, NEL]
    const int* src  = ei;
    const int* dst  = ei + NE;
    const int* lsrc = eli;
    const int* ldst = eli + NEL;

    float* out_z    = (float*)d_out;            // [NN, 32]
    float* out_pred = (float*)d_out + NN * 32;  // [NEL]

    // workspace: dinv[NN]f | off[NN]i | gcur[NBUCK]+bar[1] | csr[NE]i |
    //            hw1'[NN*64]h (aliases part[NBUCK*CAPB]i = 7.5 MB, dead after
    //            build phase; also slack for the <=15-int csr over-reads) |
    //            h2[NN*64]h (dead after hw2 phase -> reused for uu/vv) |
    //            hw2'[NN*32]h   ~= 39 MB
    float*  dinv  = (float*)d_ws;
    int*    off   = (int*)(dinv + NN);
    int*    gcur  = off + NN;
    int*    bar   = gcur + NBUCK;
    int*    csr   = bar + 1;
    __half* hw1   = (__half*)(csr + NE);
    int*    part  = (int*)hw1;                  // 7.5 MB <= hw1's 12.8 MB
    __half* h2    = hw1 + NN * 64;
    __half* hw2   = h2 + NN * 64;
    float*  uu    = (float*)h2;                 // h2 dead after hw2 phase
    float*  vv    = uu + NN;

    // node 1: zero bucket counters + grid-barrier counter
    hipMemsetAsync(gcur, 0, (NBUCK + 1) * sizeof(int), stream);

    // node 2: everything (persistent megakernel, 7 phases, 6 grid barriers)
    k_mega<<<GRID, NT, 0, stream>>>(src, dst, x, pos, W1, b1, W2, b2, Wl, bl,
                                    lsrc, ldst, gcur, bar, part, csr, off,
                                    dinv, hw1, h2, hw2, uu, vv, out_z,
                                    out_pred);
}